// Round 5
// baseline (1094.711 us; speedup 1.0000x reference)
//
#include <hip/hip_runtime.h>
#include <hip/hip_bf16.h>

#define TOKENS 2048
#define HDIM   2560
#define NEXP   16
#define IDIM   1664
#define ISDIM  3328
#define NPAIR  (TOKENS*2)

typedef float  f32x4   __attribute__((ext_vector_type(4)));
typedef __bf16 bf16x8  __attribute__((ext_vector_type(8)));
typedef short  short8v __attribute__((ext_vector_type(8)));

#define GLDS16(g, l) __builtin_amdgcn_global_load_lds( \
    (const __attribute__((address_space(1))) unsigned int*)(g), \
    (__attribute__((address_space(3))) unsigned int*)(l), 16, 0, 0)

__device__ __forceinline__ short f2bf(float f) {
  unsigned u = __builtin_bit_cast(unsigned, f);
  u += 0x7FFFu + ((u >> 16) & 1u);          // RNE to bf16
  return (short)(u >> 16);
}

// ---------------- router: fp32 logits, softmax-top2-renorm == sigmoid(l0-l1)
__global__ void router_kernel(const float* __restrict__ x, const float* __restrict__ rw,
                              int* __restrict__ counts, int* __restrict__ tidx,
                              float* __restrict__ tw) {
  const int t = blockIdx.x;
  const int lane = threadIdx.x;
  float acc[NEXP];
#pragma unroll
  for (int e = 0; e < NEXP; ++e) acc[e] = 0.f;
  const float* xr = x + (size_t)t * HDIM;
  for (int k = lane; k < HDIM; k += 64) {
    float xv = xr[k];
#pragma unroll
    for (int e = 0; e < NEXP; ++e) acc[e] += xv * rw[e * HDIM + k];
  }
#pragma unroll
  for (int e = 0; e < NEXP; ++e) {
#pragma unroll
    for (int o = 32; o > 0; o >>= 1) acc[e] += __shfl_down(acc[e], o);
  }
  if (lane == 0) {
    int i0 = 0; float v0 = acc[0];
#pragma unroll
    for (int e = 1; e < NEXP; ++e) if (acc[e] > v0) { v0 = acc[e]; i0 = e; }
    int i1 = -1; float v1 = -3.4e38f;
#pragma unroll
    for (int e = 0; e < NEXP; ++e) if (e != i0 && acc[e] > v1) { v1 = acc[e]; i1 = e; }
    float w0 = 1.f / (1.f + expf(v1 - v0));
    tidx[t * 2] = i0; tidx[t * 2 + 1] = i1;
    tw[t * 2] = w0;   tw[t * 2 + 1] = 1.f - w0;
    atomicAdd(&counts[i0], 1);
    atomicAdd(&counts[i1], 1);
  }
}

__global__ void scan_kernel(const int* __restrict__ counts, int* __restrict__ offsets) {
  if (threadIdx.x == 0) {
    int a = 0;
    for (int e = 0; e < NEXP; ++e) { offsets[e] = a; a += counts[e]; }
  }
}

// ---------------- bucket pairs + gather bf16 activations
__global__ void gather_kernel(const float* __restrict__ x, const int* __restrict__ tidx,
                              const float* __restrict__ tw, const int* __restrict__ offsets,
                              int* __restrict__ slotc, int* __restrict__ pairpos,
                              float* __restrict__ wrow, short* __restrict__ xb,
                              short* __restrict__ xg) {
  const int t = blockIdx.x, tid = threadIdx.x;
  __shared__ int grs[2];
  if (tid < 2) {
    int e = tidx[t * 2 + tid];
    int slot = atomicAdd(&slotc[e], 1);
    int g = offsets[e] + slot;
    grs[tid] = g;
    pairpos[t * 2 + tid] = g;
    wrow[g] = tw[t * 2 + tid];
  }
  __syncthreads();
  const int g0 = grs[0], g1 = grs[1];
  const float* xr = x + (size_t)t * HDIM;
#pragma unroll
  for (int i = 0; i < HDIM / 256; ++i) {
    int k = tid + i * 256;
    short v = f2bf(xr[k]);
    xb[(size_t)t * HDIM + k] = v;
    xg[(size_t)g0 * HDIM + k] = v;
    xg[(size_t)g1 * HDIM + k] = v;
  }
}

// ================= merged UP: H = bf16( silu(A*B1) * (A*B3) )
// A bf16 (M,K=2560) K-contig; B fp32 (K,N) N-contig.  BM=128, BN=64, BK=32.
// 256 threads, 4 waves (4 in M), wave tile 32x64.
// LDS 32KB: A linear [128][32] (global_load_lds); B dual [sm][n][k] with
// 16B-unit swizzle u' = u ^ ((n>>1)&3) (write+read balanced, derived).
__launch_bounds__(256, 3)
__global__ void moe_up_k(const short* __restrict__ xg, const short* __restrict__ xb,
                         const float* __restrict__ w1, const float* __restrict__ w3,
                         const float* __restrict__ sg, const float* __restrict__ su,
                         short* __restrict__ hbE, short* __restrict__ hbS,
                         const int* __restrict__ counts, const int* __restrict__ offsets) {
  const int tid = threadIdx.x;
  const int lin = blockIdx.x;
  const short* A; const float* B1; const float* B3; short* H;
  int N, mtile, ntile, rowbase = 0, cnt = 0x7fffffff;
  bool expert;
  if (lin < 26 * 32 * NEXP) {
    // 13312 = 8 XCD x 1664; m fastest -> m-siblings of an (e,n) adjacent (L2)
    int idx = (lin & 7) * 1664 + (lin >> 3);
    int m = idx & 31;
    int rest = idx >> 5;          // 0..415
    int n = rest % 26;
    int e = rest / 26;
    cnt = counts[e];
    mtile = m * 128;
    if (mtile >= cnt) return;
    rowbase = offsets[e];
    A = xg; B1 = w1 + (size_t)e * HDIM * IDIM; B3 = w3 + (size_t)e * HDIM * IDIM;
    H = hbE; N = IDIM; ntile = n * 64; expert = true;
  } else {
    int s = lin - 26 * 32 * NEXP;   // 0..831
    int n = s % 52;
    int m = s / 52;                 // 0..15
    mtile = m * 128;
    A = xb; B1 = sg; B3 = su; H = hbS; N = ISDIM; ntile = n * 64; expert = false;
  }
  const int K = HDIM;
  const int KT = HDIM / 32;

  __shared__ short Ab[2][128][32];       // 8 KB x2, linear
  __shared__ short Bb[2][2][64][32];     // 4 KB x2mat x2buf, swizzled [n][k]

  f32x4 accG[2][4], accU[2][4];
#pragma unroll
  for (int i = 0; i < 2; ++i)
#pragma unroll
    for (int j = 0; j < 4; ++j) { f32x4 z = {0.f,0.f,0.f,0.f}; accG[i][j] = z; accU[i][j] = z; }

  // A staging: 2 passes; pass p: row = (tid + p*256)>>2, k-oct = tid&3
  int a_gr[2];
#pragma unroll
  for (int p = 0; p < 2; ++p) {
    int row = ((tid + (p << 8)) >> 2);
    int gr = expert ? (rowbase + mtile + row) : (mtile + row);
    if (gr > NPAIR - 1) gr = NPAIR - 1;
    a_gr[p] = gr;
  }
  const int a_ko = (tid & 3) << 3;

  // B staging: matrix sm = tid>>7, col n = tid&63, oct-half oh = (tid>>6)&1
  const int b_sm = tid >> 7;
  const int b_n  = tid & 63;
  const int b_oh = (tid >> 6) & 1;
  const float* Bs = b_sm ? B3 : B1;
  const float* b_base = Bs + ntile + b_n;
  float bReg[2][8];

  auto stageA = [&](int kt, int buf) {
#pragma unroll
    for (int p = 0; p < 2; ++p) {
      const short* src = A + (size_t)a_gr[p] * K + (kt << 5) + a_ko;
      GLDS16(src, (short*)Ab[buf] + (tid + (p << 8)) * 8);
    }
  };
  auto loadB = [&](int kt) {
    const float* p = b_base + (size_t)(kt << 5) * N;
#pragma unroll
    for (int op = 0; op < 2; ++op)
#pragma unroll
      for (int j = 0; j < 8; ++j)
        bReg[op][j] = p[(size_t)((b_oh * 2 + op) * 8 + j) * N];
  };
  auto writeB = [&](int buf) {
#pragma unroll
    for (int op = 0; op < 2; ++op) {
      const int oct = b_oh * 2 + op;
      const int up = oct ^ ((b_n >> 1) & 3);
      short8v s;
#pragma unroll
      for (int j = 0; j < 8; ++j) s[j] = f2bf(bReg[op][j]);
      *reinterpret_cast<short8v*>(&Bb[buf][b_sm][b_n][up << 3]) = s;
    }
  };

  const int lane = tid & 63;
  const int w = tid >> 6;
  const int wm = w * 32;
  const int lrow = lane & 15;
  const int lkg = lane >> 4;

  auto compute = [&](int buf) {
    bf16x8 af[2], bG[4], bU[4];
#pragma unroll
    for (int mf = 0; mf < 2; ++mf)
      af[mf] = *reinterpret_cast<const bf16x8*>(&Ab[buf][wm + mf * 16 + lrow][lkg << 3]);
#pragma unroll
    for (int nf = 0; nf < 4; ++nf) {
      const int n = nf * 16 + lrow;
      const int kg = (lkg ^ ((n >> 1) & 3)) << 3;
      bG[nf] = *reinterpret_cast<const bf16x8*>(&Bb[buf][0][n][kg]);
      bU[nf] = *reinterpret_cast<const bf16x8*>(&Bb[buf][1][n][kg]);
    }
#pragma unroll
    for (int mf = 0; mf < 2; ++mf)
#pragma unroll
      for (int nf = 0; nf < 4; ++nf) {
        accG[mf][nf] = __builtin_amdgcn_mfma_f32_16x16x32_bf16(af[mf], bG[nf], accG[mf][nf], 0, 0, 0);
        accU[mf][nf] = __builtin_amdgcn_mfma_f32_16x16x32_bf16(af[mf], bU[nf], accU[mf][nf], 0, 0, 0);
      }
  };

  loadB(0); stageA(0, 0); writeB(0);
  __syncthreads();
  for (int kt = 0; kt < KT; ++kt) {
    const int buf = kt & 1;
    if (kt + 1 < KT) { stageA(kt + 1, buf ^ 1); loadB(kt + 1); }
    compute(buf);
    if (kt + 1 < KT) writeB(buf ^ 1);
    __syncthreads();
  }

  // epilogue: silu(g)*u -> bf16. C/D: col=lane&15, row=(lane>>4)*4+r
#pragma unroll
  for (int mf = 0; mf < 2; ++mf) {
#pragma unroll
    for (int r = 0; r < 4; ++r) {
      const int rt = wm + mf * 16 + ((lane >> 4) << 2) + r;
      if (expert && mtile + rt >= cnt) continue;
      const size_t grow = (size_t)((expert ? rowbase : 0) + mtile + rt);
      const int colb = ntile + lrow;
#pragma unroll
      for (int nf = 0; nf < 4; ++nf) {
        float g = accG[mf][nf][r];
        float u = accU[mf][nf][r];
        H[grow * N + colb + nf * 16] = f2bf(g / (1.f + expf(-g)) * u);
      }
    }
  }
}

// ================= merged DOWN: Out = A*B.  BM=128, BN=128, BK=32, 256 thr,
// 4 waves (2M x 2N), wave tile 64x64.
// expert: A=hbE (K=1664), B=w2[e], out=pairs[gr] (dense, scaled by wrow).
// shared: A=hbS (K=3328), B=sd, out=plain (combine kernel adds pairs).
__launch_bounds__(256, 3)
__global__ void moe_dn_k(const short* __restrict__ hbE, const short* __restrict__ hbS,
                         const float* __restrict__ w2, const float* __restrict__ sd,
                         float* __restrict__ pairs, float* __restrict__ outb,
                         const int* __restrict__ counts, const int* __restrict__ offsets,
                         const float* __restrict__ wrow) {
  const int tid = threadIdx.x;
  const int lin = blockIdx.x;
  const short* A; const float* B; float* Out;
  int K, KT, mtile, ntile, rowbase = 0, cnt = 0x7fffffff;
  bool expert;
  if (lin < 20 * 32 * NEXP) {
    // 10240 = 8 XCD x 1280; m fastest
    int idx = (lin & 7) * 1280 + (lin >> 3);
    int m = idx & 31;
    int rest = idx >> 5;          // 0..319
    int n = rest % 20;
    int e = rest / 20;
    cnt = counts[e];
    mtile = m * 128;
    if (mtile >= cnt) return;
    rowbase = offsets[e];
    A = hbE; B = w2 + (size_t)e * IDIM * HDIM;
    Out = pairs; K = IDIM; KT = IDIM / 32; ntile = n * 128; expert = true;
  } else {
    int s = lin - 20 * 32 * NEXP;   // 0..319
    int n = s % 20;
    int m = s / 20;                 // 0..15
    mtile = m * 128;
    A = hbS; B = sd; Out = outb; K = ISDIM; KT = ISDIM / 32; ntile = n * 128;
    expert = false;
  }

  __shared__ short Ab[2][128][32];   // 16 KB
  __shared__ short Bb[2][128][32];   // 16 KB, swizzled [n][k]

  f32x4 acc[4][4];
#pragma unroll
  for (int i = 0; i < 4; ++i)
#pragma unroll
    for (int j = 0; j < 4; ++j) { f32x4 z = {0.f,0.f,0.f,0.f}; acc[i][j] = z; }

  int a_gr[2];
#pragma unroll
  for (int p = 0; p < 2; ++p) {
    int row = ((tid + (p << 8)) >> 2);
    int gr = expert ? (rowbase + mtile + row) : (mtile + row);
    if (gr > NPAIR - 1) gr = NPAIR - 1;
    a_gr[p] = gr;
  }
  const int a_ko = (tid & 3) << 3;

  // B staging: col n = tid&127, oct-half oh = tid>>7
  const int b_n  = tid & 127;
  const int b_oh = tid >> 7;
  const float* b_base = B + ntile + b_n;
  float bReg[2][8];

  auto stageA = [&](int kt, int buf) {
#pragma unroll
    for (int p = 0; p < 2; ++p) {
      const short* src = A + (size_t)a_gr[p] * K + (kt << 5) + a_ko;
      GLDS16(src, (short*)Ab[buf] + (tid + (p << 8)) * 8);
    }
  };
  auto loadB = [&](int kt) {
    const float* p = b_base + (size_t)(kt << 5) * HDIM;
#pragma unroll
    for (int op = 0; op < 2; ++op)
#pragma unroll
      for (int j = 0; j < 8; ++j)
        bReg[op][j] = p[(size_t)((b_oh * 2 + op) * 8 + j) * HDIM];
  };
  auto writeB = [&](int buf) {
#pragma unroll
    for (int op = 0; op < 2; ++op) {
      const int oct = b_oh * 2 + op;
      const int up = oct ^ ((b_n >> 1) & 3);
      short8v s;
#pragma unroll
      for (int j = 0; j < 8; ++j) s[j] = f2bf(bReg[op][j]);
      *reinterpret_cast<short8v*>(&Bb[buf][b_n][up << 3]) = s;
    }
  };

  const int lane = tid & 63;
  const int w = tid >> 6;
  const int wm = (w >> 1) * 64;
  const int wn = (w & 1) * 64;
  const int lrow = lane & 15;
  const int lkg = lane >> 4;

  auto compute = [&](int buf) {
    bf16x8 af[4], bfv[4];
#pragma unroll
    for (int mf = 0; mf < 4; ++mf)
      af[mf] = *reinterpret_cast<const bf16x8*>(&Ab[buf][wm + mf * 16 + lrow][lkg << 3]);
#pragma unroll
    for (int nf = 0; nf < 4; ++nf) {
      const int n = wn + nf * 16 + lrow;
      const int kg = (lkg ^ ((n >> 1) & 3)) << 3;
      bfv[nf] = *reinterpret_cast<const bf16x8*>(&Bb[buf][n][kg]);
    }
#pragma unroll
    for (int mf = 0; mf < 4; ++mf)
#pragma unroll
      for (int nf = 0; nf < 4; ++nf)
        acc[mf][nf] = __builtin_amdgcn_mfma_f32_16x16x32_bf16(af[mf], bfv[nf], acc[mf][nf], 0, 0, 0);
  };

  loadB(0); stageA(0, 0); writeB(0);
  __syncthreads();
  for (int kt = 0; kt < KT; ++kt) {
    const int buf = kt & 1;
    if (kt + 1 < KT) { stageA(kt + 1, buf ^ 1); loadB(kt + 1); }
    compute(buf);
    if (kt + 1 < KT) writeB(buf ^ 1);
    __syncthreads();
  }

#pragma unroll
  for (int mf = 0; mf < 4; ++mf) {
#pragma unroll
    for (int r = 0; r < 4; ++r) {
      const int rt = wm + mf * 16 + ((lane >> 4) << 2) + r;
      const int colb = ntile + wn + lrow;
      if (expert) {
        if (mtile + rt < cnt) {
          const int gr = rowbase + mtile + rt;
          const float sc = wrow[gr];
          float* o = Out + (size_t)gr * HDIM + colb;
#pragma unroll
          for (int nf = 0; nf < 4; ++nf) o[nf * 16] = sc * acc[mf][nf][r];
        }
      } else {
        float* o = Out + (size_t)(mtile + rt) * HDIM + colb;
#pragma unroll
        for (int nf = 0; nf < 4; ++nf) o[nf * 16] = acc[mf][nf][r];
      }
    }
  }
}

// ---------------- final combine: out[t] += pairs[g0] + pairs[g1]
__global__ void combine_kernel(float* __restrict__ out, const float* __restrict__ pairs,
                               const int* __restrict__ pairpos) {
  const int t = blockIdx.x;
  const int g0 = pairpos[t * 2], g1 = pairpos[t * 2 + 1];
  const f32x4* p0 = (const f32x4*)(pairs + (size_t)g0 * HDIM);
  const f32x4* p1 = (const f32x4*)(pairs + (size_t)g1 * HDIM);
  f32x4* o = (f32x4*)(out + (size_t)t * HDIM);
  for (int c = threadIdx.x; c < HDIM / 4; c += 256)
    o[c] = o[c] + p0[c] + p1[c];
}

extern "C" void kernel_launch(void* const* d_in, const int* in_sizes, int n_in,
                              void* d_out, int out_size, void* d_ws, size_t ws_size,
                              hipStream_t stream) {
  const float* x  = (const float*)d_in[0];
  const float* rw = (const float*)d_in[1];
  const float* w1 = (const float*)d_in[2];
  const float* w3 = (const float*)d_in[3];
  const float* w2 = (const float*)d_in[4];
  const float* sg = (const float*)d_in[5];
  const float* su = (const float*)d_in[6];
  const float* sd = (const float*)d_in[7];
  float* out = (float*)d_out;
  (void)in_sizes; (void)n_in; (void)out_size; (void)ws_size;

  char* ws = (char*)d_ws;
  size_t off = 0;
  auto alloc = [&](size_t bytes) -> void* {
    void* p = ws + off;
    off = (off + bytes + 255) & ~(size_t)255;
    return p;
  };
  int*   counts  = (int*)alloc(NEXP * 4);          // @0
  int*   slotc   = (int*)alloc(NEXP * 4);          // @256
  int*   offsets = (int*)alloc(NEXP * 4);
  int*   tidx    = (int*)alloc(NPAIR * 4);
  float* tw      = (float*)alloc(NPAIR * 4);
  float* wrowv   = (float*)alloc(NPAIR * 4);
  int*   pairpos = (int*)alloc(NPAIR * 4);
  short* xb      = (short*)alloc((size_t)TOKENS * HDIM * 2);
  short* xg      = (short*)alloc((size_t)NPAIR * HDIM * 2);
  short* hbE     = (short*)alloc((size_t)NPAIR * IDIM * 2);
  short* hbS     = (short*)alloc((size_t)TOKENS * ISDIM * 2);
  float* pairs   = (float*)alloc((size_t)NPAIR * HDIM * 4);

  hipMemsetAsync(d_ws, 0, 512, stream);  // zero counts + slotc

  router_kernel<<<dim3(TOKENS), dim3(64), 0, stream>>>(x, rw, counts, tidx, tw);
  scan_kernel<<<dim3(1), dim3(64), 0, stream>>>(counts, offsets);
  gather_kernel<<<dim3(TOKENS), dim3(256), 0, stream>>>(x, tidx, tw, offsets, slotc,
                                                        pairpos, wrowv, xb, xg);

  // merged up: experts (32m x 26n x 16e = 13312) + shared (832)
  moe_up_k<<<dim3(26 * 32 * NEXP + 832), dim3(256), 0, stream>>>(
      xg, xb, w1, w3, sg, su, hbE, hbS, counts, offsets);

  // merged down: experts (32m x 20n x 16e = 10240) + shared (320)
  moe_dn_k<<<dim3(20 * 32 * NEXP + 320), dim3(256), 0, stream>>>(
      hbE, hbS, w2, sd, pairs, out, counts, offsets, wrowv);

  combine_kernel<<<dim3(TOKENS), dim3(256), 0, stream>>>(out, pairs, pairpos);
}